// Round 2
// baseline (610.630 us; speedup 1.0000x reference)
//
#include <hip/hip_runtime.h>
#include <hip/hip_bf16.h>

// HalfEdgeConv: out[E,256] = relu(concat(x[idx[e,0..3]]) @ W[512,256] + b)
// bf16 split-precision MFMA (Ah*Bh + Ah*Bl + Al*Bh). Round 2: 64x64 wave
// tiles (mf=4,nf=4), 256-thread blocks, 4 blocks/CU; coalesced prep_w.

#define E_ROWS 262144
#define C_IN   128
#define KN     4
#define O_OUT  256
#define BM     128
#define BN     128
#define BK     32
#define NSTEPS 16
#define NT     256    // 4 waves: 2(M) x 2(N); wave tile 64x64

typedef __attribute__((ext_vector_type(8))) short bf16x8;
typedef __attribute__((ext_vector_type(4))) float f32x4;

__device__ __forceinline__ unsigned short bf16_rne(float f) {
    unsigned u = __float_as_uint(f);
    return (unsigned short)((u + 0x7fffu + ((u >> 16) & 1u)) >> 16);
}

// Coalesced W prep: one block per K-step. Loads W[s*32..s*32+31][0..255]
// with float4 coalesced reads into padded LDS, then emits swizzled bf16
// hi/lo chunk images. Image layout (uint4 units):
//   wimg[nb*16384 + (2*s+h)*512 + cl], cl: nl=cl>>2, cs=cl&3,
//   source k-chunk c = cs ^ ((nl>>1)&3), chunk = 8 k's of col n=nb*128+nl.
__global__ void prep_w(const float* __restrict__ W, uint4* __restrict__ wimg) {
    __shared__ float Ws[32][260];   // +4 pad: bank spread, keeps 16B align
    const int s = blockIdx.x;
    const int t = threadIdx.x;
    #pragma unroll
    for (int i = 0; i < 8; ++i) {
        int v4 = i * 256 + t;            // 0..2047 float4s
        int k  = v4 >> 6;
        int n4 = v4 & 63;
        float4 w = ((const float4*)W)[(size_t)(s * 32 + k) * 64 + n4];
        *(float4*)&Ws[k][n4 * 4] = w;
    }
    __syncthreads();
    #pragma unroll
    for (int i = 0; i < 8; ++i) {
        int q  = i * 256 + t;            // 0..2047 output chunks this step
        int nb = q >> 10;
        int h  = (q >> 9) & 1;
        int cl = q & 511;
        int nl = cl >> 2;
        int cs = cl & 3;
        int c  = cs ^ ((nl >> 1) & 3);
        int n  = nb * 128 + nl;
        int kb = c * 8;
        unsigned short v[8];
        #pragma unroll
        for (int e = 0; e < 8; ++e) {
            float w = Ws[kb + e][n];
            unsigned u  = __float_as_uint(w);
            unsigned hb = (u + 0x7fffu + ((u >> 16) & 1u)) & 0xffff0000u;
            float r = w - __uint_as_float(hb);
            v[e] = h ? bf16_rne(r) : (unsigned short)(hb >> 16);
        }
        uint4 o;
        o.x = (unsigned)v[0] | ((unsigned)v[1] << 16);
        o.y = (unsigned)v[2] | ((unsigned)v[3] << 16);
        o.z = (unsigned)v[4] | ((unsigned)v[5] << 16);
        o.w = (unsigned)v[6] | ((unsigned)v[7] << 16);
        wimg[(size_t)nb * 16384 + (size_t)(2 * s + h) * 512 + cl] = o;
    }
}

__global__ __launch_bounds__(NT, 4) void gemm(
    const float* __restrict__ x,
    const int* __restrict__ nidx,
    const uint4* __restrict__ wimg,
    const float* __restrict__ bias,
    float* __restrict__ out)
{
    __shared__ __align__(16) float A_s[BM * BK];              // 16 KB fp32 (swizzled chunks)
    __shared__ __align__(16) unsigned short B_s[2 * BN * BK]; // hi 8KB + lo 8KB
    __shared__ int   idx_s[BM * KN];                          // 2 KB
    __shared__ float b_s[BN];

    const int t  = threadIdx.x;
    const int m0 = blockIdx.x * BM;
    const int nb = blockIdx.y;
    const int n0 = nb * BN;

    idx_s[t]       = nidx[(size_t)m0 * KN + t];
    idx_s[t + 256] = nidx[(size_t)m0 * KN + 256 + t];
    if (t < BN) b_s[t] = bias[n0 + t];

    const int l   = t & 63;
    const int wid = t >> 6;     // 0..3
    const int wm  = wid >> 1;   // 0..1 (M)
    const int wn  = wid & 1;    // 0..1 (N)
    const int lr  = l & 15;
    const int lg  = l >> 4;

    // A staging: thread stages chunks q = t + 256*i, i=0..3.
    // LDS pos cs=q&7 of row q>>3 holds source chunk c = cs ^ (row&7).
    int arow[4], ac[4];
    #pragma unroll
    for (int i = 0; i < 4; ++i) {
        int q   = t + 256 * i;
        arow[i] = q >> 3;
        ac[i]   = (q & 7) ^ (arow[i] & 7);
    }

    const uint4* wbase = wimg + (size_t)nb * 16384;

    f32x4 acc[4][4];
    #pragma unroll
    for (int i = 0; i < 4; ++i)
        #pragma unroll
        for (int jj = 0; jj < 4; ++jj)
            acc[i][jj] = (f32x4){0.f, 0.f, 0.f, 0.f};

    char* Abase = (char*)&A_s[0];
    char* Bbase = (char*)&B_s[0];

    __syncthreads();

    #pragma unroll 1
    for (int s = 0; s < NSTEPS; ++s) {
        const int j  = s >> 2;
        const int kc = (s & 3) << 5;

        // ---- stage A (gathered fp32 rows, swizzled source -> linear LDS) ----
        #pragma unroll
        for (int i = 0; i < 4; ++i) {
            const float* src = x + (size_t)idx_s[arow[i] * KN + j] * C_IN + kc + (ac[i] << 2);
            __builtin_amdgcn_global_load_lds(
                (const __attribute__((address_space(1))) void*)src,
                (__attribute__((address_space(3))) void*)(Abase + (i << 12) + (wid << 10)),
                16, 0, 0);
        }
        // ---- stage B (linear copy of pre-swizzled image) ----
        #pragma unroll
        for (int i = 0; i < 2; ++i) {
            const uint4* srcH = wbase + (size_t)(2 * s) * 512 + (t + 256 * i);
            const uint4* srcL = wbase + (size_t)(2 * s + 1) * 512 + (t + 256 * i);
            __builtin_amdgcn_global_load_lds(
                (const __attribute__((address_space(1))) void*)srcH,
                (__attribute__((address_space(3))) void*)(Bbase + (i << 12) + (wid << 10)),
                16, 0, 0);
            __builtin_amdgcn_global_load_lds(
                (const __attribute__((address_space(1))) void*)srcL,
                (__attribute__((address_space(3))) void*)(Bbase + 8192 + (i << 12) + (wid << 10)),
                16, 0, 0);
        }
        __syncthreads();   // drains vmcnt; staged data visible CU-wide

        // ---- B fragments: 8 ds_read_b128, held across mf loop ----
        bf16x8 bh[4], bl[4];
        #pragma unroll
        for (int nf = 0; nf < 4; ++nf) {
            int nl  = (wn << 6) + (nf << 4) + lr;
            int cB  = lg ^ ((nl >> 1) & 3);
            int off = nl * 64 + cB * 16;
            bh[nf] = *(const bf16x8*)(Bbase + off);
            bl[nf] = *(const bf16x8*)(Bbase + 8192 + off);
        }

        // ---- A: read fp32, split hi/lo in-register, 12 MFMA per mf ----
        #pragma unroll
        for (int mf = 0; mf < 4; ++mf) {
            int row = (wm << 6) + (mf << 4) + lr;
            int c0  = (lg << 1) ^ (lr & 7);
            f32x4 a0 = *(const f32x4*)(Abase + row * 128 + c0 * 16);
            f32x4 a1 = *(const f32x4*)(Abase + row * 128 + (c0 ^ 1) * 16);
            float av[8];
            av[0]=a0[0]; av[1]=a0[1]; av[2]=a0[2]; av[3]=a0[3];
            av[4]=a1[0]; av[5]=a1[1]; av[6]=a1[2]; av[7]=a1[3];
            bf16x8 ah, al;
            #pragma unroll
            for (int e = 0; e < 8; ++e) {
                unsigned u  = __float_as_uint(av[e]);
                unsigned hb = u & 0xffff0000u;        // truncated hi (exact split)
                ah[e] = (short)(u >> 16);
                al[e] = (short)bf16_rne(av[e] - __uint_as_float(hb));
            }
            #pragma unroll
            for (int nf = 0; nf < 4; ++nf) {
                acc[mf][nf] = __builtin_amdgcn_mfma_f32_16x16x32_bf16(ah, bh[nf], acc[mf][nf], 0, 0, 0);
                acc[mf][nf] = __builtin_amdgcn_mfma_f32_16x16x32_bf16(ah, bl[nf], acc[mf][nf], 0, 0, 0);
                acc[mf][nf] = __builtin_amdgcn_mfma_f32_16x16x32_bf16(al, bh[nf], acc[mf][nf], 0, 0, 0);
            }
        }
        __syncthreads();
    }

    // ---- epilogue: bias + relu; D layout col=lane&15, row=(lane>>4)*4+r ----
    #pragma unroll
    for (int mf = 0; mf < 4; ++mf) {
        #pragma unroll
        for (int nf = 0; nf < 4; ++nf) {
            int colL = (wn << 6) + (nf << 4) + lr;
            int col  = n0 + colL;
            float bv = b_s[colL];
            int rowb = m0 + (wm << 6) + (mf << 4) + (lg << 2);
            #pragma unroll
            for (int r = 0; r < 4; ++r) {
                float v = acc[mf][nf][r] + bv;
                out[(size_t)(rowb + r) * O_OUT + col] = fmaxf(v, 0.f);
            }
        }
    }
}

extern "C" void kernel_launch(void* const* d_in, const int* in_sizes, int n_in,
                              void* d_out, int out_size, void* d_ws, size_t ws_size,
                              hipStream_t stream) {
    const float* x    = (const float*)d_in[0];
    const int*   nidx = (const int*)d_in[1];
    const float* W    = (const float*)d_in[2];
    const float* bias = (const float*)d_in[3];
    float* out  = (float*)d_out;
    uint4* wimg = (uint4*)d_ws;   // 512 KB of ws

    hipLaunchKernelGGL(prep_w, dim3(NSTEPS), dim3(256), 0, stream, W, wimg);
    hipLaunchKernelGGL(gemm, dim3(E_ROWS / BM, O_OUT / BN), dim3(NT), 0, stream,
                       x, nidx, wimg, bias, out);
}

// Round 6
// 543.078 us; speedup vs baseline: 1.1244x; 1.1244x over previous
//
#include <hip/hip_runtime.h>
#include <hip/hip_bf16.h>

// HalfEdgeConv: out[E,256] = relu(concat(x[idx[e,0..3]]) @ W[512,256] + b)
// bf16 split-precision MFMA (Ah*Bh + Ah*Bl + Al*Bh). Round 3 kernel,
// resubmitted again (rounds 3-5 all hit GPU acquisition timeouts; the
// 2-phase pipeline has never executed): 512 thr, 8 waves, 32x64 wave tile
// + double-buffered LDS with 2-phase prefetch pipeline -> ONE barrier per
// K-step, gather latency overlapped with MFMA instead of drained.

#define E_ROWS 262144
#define C_IN   128
#define KN     4
#define O_OUT  256
#define BM     128
#define BN     128
#define BK     32
#define NSTEPS 16
#define NT     512    // 8 waves: 4(M) x 2(N); wave tile 32x64

typedef __attribute__((ext_vector_type(8))) short bf16x8;
typedef __attribute__((ext_vector_type(4))) float f32x4;

__device__ __forceinline__ unsigned short bf16_rne(float f) {
    unsigned u = __float_as_uint(f);
    return (unsigned short)((u + 0x7fffu + ((u >> 16) & 1u)) >> 16);
}

// Coalesced W prep: one block per K-step. float4 loads into padded LDS,
// emits swizzled bf16 hi/lo chunk images. Image layout (uint4 units):
//   wimg[nb*16384 + (2*s+h)*512 + cl], nl=cl>>2, cs=cl&3,
//   source k-chunk c = cs ^ ((nl>>1)&3), chunk = 8 k's of col n=nb*128+nl.
__global__ void prep_w(const float* __restrict__ W, uint4* __restrict__ wimg) {
    __shared__ float Ws[32][260];
    const int s = blockIdx.x;
    const int t = threadIdx.x;
    #pragma unroll
    for (int i = 0; i < 8; ++i) {
        int v4 = i * 256 + t;
        int k  = v4 >> 6;
        int n4 = v4 & 63;
        float4 w = ((const float4*)W)[(size_t)(s * 32 + k) * 64 + n4];
        *(float4*)&Ws[k][n4 * 4] = w;
    }
    __syncthreads();
    #pragma unroll
    for (int i = 0; i < 8; ++i) {
        int q  = i * 256 + t;
        int nb = q >> 10;
        int h  = (q >> 9) & 1;
        int cl = q & 511;
        int nl = cl >> 2;
        int cs = cl & 3;
        int c  = cs ^ ((nl >> 1) & 3);
        int n  = nb * 128 + nl;
        int kb = c * 8;
        unsigned short v[8];
        #pragma unroll
        for (int e = 0; e < 8; ++e) {
            float w = Ws[kb + e][n];
            unsigned u  = __float_as_uint(w);
            unsigned hb = (u + 0x7fffu + ((u >> 16) & 1u)) & 0xffff0000u;
            float r = w - __uint_as_float(hb);
            v[e] = h ? bf16_rne(r) : (unsigned short)(hb >> 16);
        }
        uint4 o;
        o.x = (unsigned)v[0] | ((unsigned)v[1] << 16);
        o.y = (unsigned)v[2] | ((unsigned)v[3] << 16);
        o.z = (unsigned)v[4] | ((unsigned)v[5] << 16);
        o.w = (unsigned)v[6] | ((unsigned)v[7] << 16);
        wimg[(size_t)nb * 16384 + (size_t)(2 * s + h) * 512 + cl] = o;
    }
}

__global__ __launch_bounds__(NT, 4) void gemm(
    const float* __restrict__ x,
    const int* __restrict__ nidx,
    const uint4* __restrict__ wimg,
    const float* __restrict__ bias,
    float* __restrict__ out)
{
    __shared__ __align__(16) float A_s[2][BM * BK];              // 2 x 16 KB
    __shared__ __align__(16) unsigned short B_s[2][2 * BN * BK]; // 2 x 16 KB
    __shared__ int   idx_s[BM * KN];                             // 2 KB
    __shared__ float b_s[BN];

    const int t  = threadIdx.x;
    const int m0 = blockIdx.x * BM;
    const int nb = blockIdx.y;
    const int n0 = nb * BN;

    idx_s[t] = nidx[(size_t)m0 * KN + t];    // BM*KN == 512 == NT
    if (t < BN) b_s[t] = bias[n0 + t];

    const int l   = t & 63;
    const int wid = t >> 6;     // 0..7
    const int wm  = wid >> 1;   // 0..3 (M)
    const int wn  = wid & 1;    // 0..1 (N)
    const int lr  = l & 15;
    const int lg  = l >> 4;

    // A staging: thread stages chunks q=t and q=512+t.
    // LDS pos cs=q&7 of row q>>3 holds source chunk c = cs ^ (row&7).
    const int arow0 = t >> 3;
    const int ac0   = (t & 7) ^ (arow0 & 7);
    const int arow1 = (512 + t) >> 3;
    const int ac1   = ((512 + t) & 7) ^ (arow1 & 7);

    const uint4* wbase = wimg + (size_t)nb * 16384;

    f32x4 acc[2][4];
    #pragma unroll
    for (int i = 0; i < 2; ++i)
        #pragma unroll
        for (int jj = 0; jj < 4; ++jj)
            acc[i][jj] = (f32x4){0.f, 0.f, 0.f, 0.f};

    char* Aall = (char*)&A_s[0][0];
    char* Ball = (char*)&B_s[0][0];

    // Issue the 4 staging loads for K-step s into buffer `buf`.
    auto STAGE = [&](int s, int buf) {
        const int j  = s >> 2;
        const int kc = (s & 3) << 5;
        char* Ab = Aall + (buf << 14);
        char* Bb = Ball + (buf << 14);
        const float* a0p = x + (size_t)idx_s[arow0 * KN + j] * C_IN + kc + (ac0 << 2);
        const float* a1p = x + (size_t)idx_s[arow1 * KN + j] * C_IN + kc + (ac1 << 2);
        __builtin_amdgcn_global_load_lds(
            (const __attribute__((address_space(1))) void*)a0p,
            (__attribute__((address_space(3))) void*)(Ab + (wid << 10)), 16, 0, 0);
        __builtin_amdgcn_global_load_lds(
            (const __attribute__((address_space(1))) void*)a1p,
            (__attribute__((address_space(3))) void*)(Ab + 8192 + (wid << 10)), 16, 0, 0);
        const uint4* sH = wbase + (size_t)(2 * s) * 512 + t;
        const uint4* sL = wbase + (size_t)(2 * s + 1) * 512 + t;
        __builtin_amdgcn_global_load_lds(
            (const __attribute__((address_space(1))) void*)sH,
            (__attribute__((address_space(3))) void*)(Bb + (wid << 10)), 16, 0, 0);
        __builtin_amdgcn_global_load_lds(
            (const __attribute__((address_space(1))) void*)sL,
            (__attribute__((address_space(3))) void*)(Bb + 8192 + (wid << 10)), 16, 0, 0);
    };

    // ds_read fragments from buffer `buf`, split, 24 MFMAs.
    auto COMPUTE = [&](int buf) {
        char* Ab = Aall + (buf << 14);
        char* Bb = Ball + (buf << 14);
        bf16x8 bh[4], bl[4];
        #pragma unroll
        for (int nf = 0; nf < 4; ++nf) {
            int nl  = (wn << 6) + (nf << 4) + lr;
            int cB  = lg ^ ((nl >> 1) & 3);
            int off = nl * 64 + cB * 16;
            bh[nf] = *(const bf16x8*)(Bb + off);
            bl[nf] = *(const bf16x8*)(Bb + 8192 + off);
        }
        #pragma unroll
        for (int mf = 0; mf < 2; ++mf) {
            int row = (wm << 5) + (mf << 4) + lr;
            int c0  = (lg << 1) ^ (row & 7);
            f32x4 a0 = *(const f32x4*)(Ab + row * 128 + c0 * 16);
            f32x4 a1 = *(const f32x4*)(Ab + row * 128 + (c0 ^ 1) * 16);
            float av[8];
            av[0]=a0[0]; av[1]=a0[1]; av[2]=a0[2]; av[3]=a0[3];
            av[4]=a1[0]; av[5]=a1[1]; av[6]=a1[2]; av[7]=a1[3];
            bf16x8 ah, al;
            #pragma unroll
            for (int e = 0; e < 8; ++e) {
                unsigned u  = __float_as_uint(av[e]);
                unsigned hb = u & 0xffff0000u;        // truncated hi (exact split)
                ah[e] = (short)(u >> 16);
                al[e] = (short)bf16_rne(av[e] - __uint_as_float(hb));
            }
            #pragma unroll
            for (int nf = 0; nf < 4; ++nf) {
                acc[mf][nf] = __builtin_amdgcn_mfma_f32_16x16x32_bf16(ah, bh[nf], acc[mf][nf], 0, 0, 0);
                acc[mf][nf] = __builtin_amdgcn_mfma_f32_16x16x32_bf16(ah, bl[nf], acc[mf][nf], 0, 0, 0);
                acc[mf][nf] = __builtin_amdgcn_mfma_f32_16x16x32_bf16(al, bh[nf], acc[mf][nf], 0, 0, 0);
            }
        }
    };

    __syncthreads();          // idx_s/b_s visible
    STAGE(0, 0);
    __syncthreads();          // prologue tile landed (vmcnt drain)

    // 2-phase pipeline, unrolled x2 so buffer selector is compile-time.
    #pragma unroll 1
    for (int s = 0; s < NSTEPS; s += 2) {
        if (s + 1 < NSTEPS) STAGE(s + 1, 1);   // prefetch next into buf1
        COMPUTE(0);                            // consume buf0 (hides prefetch)
        __syncthreads();                       // single drain: prefetch landed
        if (s + 2 < NSTEPS) STAGE(s + 2, 0);   // prefetch into buf0
        COMPUTE(1);                            // consume buf1
        __syncthreads();
    }

    // ---- epilogue: bias + relu; D layout col=lane&15, row=(lane>>4)*4+r ----
    #pragma unroll
    for (int mf = 0; mf < 2; ++mf) {
        #pragma unroll
        for (int nf = 0; nf < 4; ++nf) {
            int colL = (wn << 6) + (nf << 4) + lr;
            int col  = n0 + colL;
            float bv = b_s[colL];
            int rowb = m0 + (wm << 5) + (mf << 4) + (lg << 2);
            #pragma unroll
            for (int r = 0; r < 4; ++r) {
                float v = acc[mf][nf][r] + bv;
                out[(size_t)(rowb + r) * O_OUT + col] = fmaxf(v, 0.f);
            }
        }
    }
}

extern "C" void kernel_launch(void* const* d_in, const int* in_sizes, int n_in,
                              void* d_out, int out_size, void* d_ws, size_t ws_size,
                              hipStream_t stream) {
    const float* x    = (const float*)d_in[0];
    const int*   nidx = (const int*)d_in[1];
    const float* W    = (const float*)d_in[2];
    const float* bias = (const float*)d_in[3];
    float* out  = (float*)d_out;
    uint4* wimg = (uint4*)d_ws;   // 512 KB of ws

    hipLaunchKernelGGL(prep_w, dim3(NSTEPS), dim3(256), 0, stream, W, wimg);
    hipLaunchKernelGGL(gemm, dim3(E_ROWS / BM, O_OUT / BN), dim3(NT), 0, stream,
                       x, nidx, wimg, bias, out);
}